// Round 1
// baseline (421.198 us; speedup 1.0000x reference)
//
#include <hip/hip_runtime.h>
#include <math.h>

#define HSZ 4096
#define CHUNK 128            // K rows per block
#define COLS_PER_BLOCK 1024  // 256 threads * 4 cols (float4)
#define NBLK_PER_MAT 128     // 4 col-tiles * 32 k-chunks

struct WPtrs { const float* W[8]; };
struct BPtrs { const float* b[8]; };

// --- 1. h != 0 flag ---------------------------------------------------------
__global__ void lstm_flag_kernel(const float* __restrict__ h, int* __restrict__ flag) {
    __shared__ int s;
    if (threadIdx.x == 0) s = 0;
    __syncthreads();
    int any = 0;
    for (int i = threadIdx.x; i < HSZ; i += 256) any |= (h[i] != 0.0f);
    if (__any(any)) {
        if ((threadIdx.x & 63) == 0) atomicOr(&s, 1);
    }
    __syncthreads();
    if (threadIdx.x == 0) *flag = s;
}

// --- 2. gates = b_i + b_h ---------------------------------------------------
__global__ void lstm_init_gates(BPtrs bp, float* __restrict__ gates) {
    int j = blockIdx.x * 256 + threadIdx.x;       // [0, 16384)
    int gate = j >> 12;                           // wave-uniform (block-uniform)
    int col  = j & (HSZ - 1);
    gates[j] = bp.b[gate][col] + bp.b[gate + 4][col];
}

// --- 3. partial GEMV, atomic accumulate into gates --------------------------
__global__ __launch_bounds__(256) void lstm_gemv_kernel(
        WPtrs wp, const float* __restrict__ x, const float* __restrict__ hv,
        float* __restrict__ gates, const int* __restrict__ flag) {
    int mat = blockIdx.x >> 7;        // 0..7 : Wii,Wif,Wig,Wio,Whi,Whf,Whg,Who
    int rem = blockIdx.x & (NBLK_PER_MAT - 1);
    if (mat >= 4 && *flag == 0) return;   // h == 0 -> h@Wh == 0, skip read
    int ct = rem & 3;                 // column tile
    int kc = rem >> 2;                // k chunk
    const float* __restrict__ W = wp.W[mat];
    const float* __restrict__ v = (mat < 4) ? x : hv;

    __shared__ float vs[CHUNK];
    if (threadIdx.x < CHUNK) vs[threadIdx.x] = v[kc * CHUNK + threadIdx.x];
    __syncthreads();

    int col = ct * COLS_PER_BLOCK + threadIdx.x * 4;
    const float* Wp = W + (size_t)kc * CHUNK * HSZ + col;
    float4 acc = make_float4(0.f, 0.f, 0.f, 0.f);
#pragma unroll 8
    for (int k = 0; k < CHUNK; ++k) {
        float4 w = *(const float4*)(Wp + (size_t)k * HSZ);
        float xv = vs[k];
        acc.x = fmaf(xv, w.x, acc.x);
        acc.y = fmaf(xv, w.y, acc.y);
        acc.z = fmaf(xv, w.z, acc.z);
        acc.w = fmaf(xv, w.w, acc.w);
    }
    float* g = gates + (size_t)(mat & 3) * HSZ + col;
    atomicAdd(g + 0, acc.x);
    atomicAdd(g + 1, acc.y);
    atomicAdd(g + 2, acc.z);
    atomicAdd(g + 3, acc.w);
}

// --- 4. activations + cell update -------------------------------------------
__device__ __forceinline__ float sigmoidf_fast(float v) {
    return 1.0f / (1.0f + __expf(-v));
}

__global__ void lstm_final_kernel(const float* __restrict__ gates,
                                  const float* __restrict__ c,
                                  float* __restrict__ out) {
    int j = blockIdx.x * 256 + threadIdx.x;   // [0, 4096)
    float ig = gates[j];
    float fg = gates[HSZ + j];
    float gg = gates[2 * HSZ + j];
    float og = gates[3 * HSZ + j];
    float it = sigmoidf_fast(ig);
    float ft = sigmoidf_fast(fg);
    float gt = tanhf(gg);
    float ot = sigmoidf_fast(og);
    float cn = ft * c[j] + it * gt;
    out[j] = ot * tanhf(cn);
}

extern "C" void kernel_launch(void* const* d_in, const int* in_sizes, int n_in,
                              void* d_out, int out_size, void* d_ws, size_t ws_size,
                              hipStream_t stream) {
    const float* x = (const float*)d_in[0];
    WPtrs wp;
    for (int i = 0; i < 8; ++i) wp.W[i] = (const float*)d_in[1 + i];   // Wii..Who
    BPtrs bp;
    for (int i = 0; i < 8; ++i) bp.b[i] = (const float*)d_in[9 + i];   // bii..bho
    const float* h = (const float*)d_in[17];
    const float* c = (const float*)d_in[18];

    float* gates = (float*)d_ws;                 // 16384 floats
    int*   flag  = (int*)d_ws + 4 * HSZ;         // 1 int after gates

    lstm_flag_kernel<<<1, 256, 0, stream>>>(h, flag);
    lstm_init_gates<<<(4 * HSZ) / 256, 256, 0, stream>>>(bp, gates);
    lstm_gemv_kernel<<<8 * NBLK_PER_MAT, 256, 0, stream>>>(wp, x, h, gates, flag);
    lstm_final_kernel<<<HSZ / 256, 256, 0, stream>>>(gates, c, (float*)d_out);
}

// Round 2
// 412.762 us; speedup vs baseline: 1.0204x; 1.0204x over previous
//
#include <hip/hip_runtime.h>
#include <math.h>

#define HSZ 4096
#define CHUNK 64             // K rows per block
#define COLS_PER_BLOCK 1024  // 256 threads * 4 cols (float4)
#define NBLK_PER_MAT 256     // 4 col-tiles * 64 k-chunks

struct WPtrs { const float* W[8]; };
struct BPtrs { const float* b[8]; };

// --- partial GEMV, atomic accumulate into gates -----------------------------
// gates must be zeroed before launch. Each block checks its own 64-element
// chunk of the input vector; all-zero chunk => contribution is zero => skip
// reading the 64x1024 weight slab entirely (handles h_t == 0 generically).
__global__ __launch_bounds__(256) void lstm_gemv_kernel(
        WPtrs wp, const float* __restrict__ x, const float* __restrict__ hv,
        float* __restrict__ gates) {
    int mat = blockIdx.x >> 8;               // 0..7 : Wii,Wif,Wig,Wio,Whi,Whf,Whg,Who
    int rem = blockIdx.x & (NBLK_PER_MAT - 1);
    int ct  = rem & 3;                       // column tile
    int kc  = rem >> 2;                      // k chunk
    const float* __restrict__ W = wp.W[mat];
    const float* __restrict__ v = (mat < 4) ? x : hv;

    __shared__ float vs[CHUNK];
    __shared__ int nz;
    int tid = threadIdx.x;
    if (tid == 0) nz = 0;
    __syncthreads();
    if (tid < CHUNK) {                       // wave 0 only (CHUNK == 64)
        float val = v[kc * CHUNK + tid];
        vs[tid] = val;
        if (__any(val != 0.0f) && tid == 0) nz = 1;
    }
    __syncthreads();
    if (!nz) return;                         // whole chunk zero -> skip weights

    int col = ct * COLS_PER_BLOCK + tid * 4;
    const float* Wp = W + (size_t)kc * CHUNK * HSZ + col;
    float4 acc = make_float4(0.f, 0.f, 0.f, 0.f);
#pragma unroll
    for (int kk = 0; kk < CHUNK; kk += 8) {
        float4 w[8];
#pragma unroll
        for (int u = 0; u < 8; ++u)
            w[u] = *(const float4*)(Wp + (size_t)(kk + u) * HSZ);
#pragma unroll
        for (int u = 0; u < 8; ++u) {
            float xv = vs[kk + u];
            acc.x = fmaf(xv, w[u].x, acc.x);
            acc.y = fmaf(xv, w[u].y, acc.y);
            acc.z = fmaf(xv, w[u].z, acc.z);
            acc.w = fmaf(xv, w[u].w, acc.w);
        }
    }
    float* g = gates + (size_t)(mat & 3) * HSZ + col;
    atomicAdd(g + 0, acc.x);
    atomicAdd(g + 1, acc.y);
    atomicAdd(g + 2, acc.z);
    atomicAdd(g + 3, acc.w);
}

// --- biases + activations + cell update -------------------------------------
__device__ __forceinline__ float sigmoidf_fast(float v) {
    return 1.0f / (1.0f + __expf(-v));
}

__global__ void lstm_final_kernel(const float* __restrict__ gates, BPtrs bp,
                                  const float* __restrict__ c,
                                  float* __restrict__ out) {
    int j = blockIdx.x * 256 + threadIdx.x;   // [0, 4096)
    float ig = gates[j]           + bp.b[0][j] + bp.b[4][j];
    float fg = gates[HSZ + j]     + bp.b[1][j] + bp.b[5][j];
    float gg = gates[2 * HSZ + j] + bp.b[2][j] + bp.b[6][j];
    float og = gates[3 * HSZ + j] + bp.b[3][j] + bp.b[7][j];
    float it = sigmoidf_fast(ig);
    float ft = sigmoidf_fast(fg);
    float gt = tanhf(gg);
    float ot = sigmoidf_fast(og);
    float cn = ft * c[j] + it * gt;
    out[j] = ot * tanhf(cn);
}

extern "C" void kernel_launch(void* const* d_in, const int* in_sizes, int n_in,
                              void* d_out, int out_size, void* d_ws, size_t ws_size,
                              hipStream_t stream) {
    const float* x = (const float*)d_in[0];
    WPtrs wp;
    for (int i = 0; i < 8; ++i) wp.W[i] = (const float*)d_in[1 + i];   // Wii..Who
    BPtrs bp;
    for (int i = 0; i < 8; ++i) bp.b[i] = (const float*)d_in[9 + i];   // bii..bho
    const float* h = (const float*)d_in[17];
    const float* c = (const float*)d_in[18];

    float* gates = (float*)d_ws;                 // 16384 floats, zeroed below

    hipMemsetAsync(gates, 0, 4 * HSZ * sizeof(float), stream);
    lstm_gemv_kernel<<<8 * NBLK_PER_MAT, 256, 0, stream>>>(wp, x, h, gates);
    lstm_final_kernel<<<HSZ / 256, 256, 0, stream>>>(gates, bp, c, (float*)d_out);
}